// Round 5
// baseline (158.209 us; speedup 1.0000x reference)
//
#include <hip/hip_runtime.h>
#include <hip/hip_fp16.h>

#define BATCH 4096
#define NTRI  128
#define DIM   64
#define NENT  100000
#define WTH   1e-5f   // item-side: drop tail-gathers with softmax weight below this

typedef int   v2i __attribute__((ext_vector_type(2)));
typedef float v4f __attribute__((ext_vector_type(4)));

// LDS: per-wave-private except res/anchors (guarded by the single __syncthreads).
struct Smem {
    int   idx[4][2 * NTRI];   // per-set: h in [0..127], t in [128..255]
    int   meanidx[NTRI];      // wave-1 private copy of user layer-0 h indices
    float simw[4][NTRI];      // sims -> weights, permuted: pos = k*8+oct
    int   cidx[2][NTRI];      // item-wave compacted t-indices (waves 2,3)
    float cw[2][NTRI];        // item-wave compacted weights
    float res[4][DIM];        // per-wave attention results
    float anch_u[DIM];        // user_0 mean   (written by wave 0)
    float anch_v[DIM];        // item origin   (written by wave 2)
};

// ---- fp32 -> fp16 table conversion (every launch; d_ws is re-poisoned) ----
__global__ __launch_bounds__(256) void convert_fp16(
    const float* __restrict__ src, __half* __restrict__ dst, int n8) {
    const int i = blockIdx.x * 256 + threadIdx.x;   // 8 floats per thread
    if (i >= n8) return;
    const v4f a = __builtin_nontemporal_load((const v4f*)src + 2 * i);
    const v4f b = __builtin_nontemporal_load((const v4f*)src + 2 * i + 1);
    __half2 h0 = __floats2half2_rn(a.x, a.y);
    __half2 h1 = __floats2half2_rn(a.z, a.w);
    __half2 h2 = __floats2half2_rn(b.x, b.y);
    __half2 h3 = __floats2half2_rn(b.z, b.w);
    uint4 o;
    o.x = *(const unsigned*)&h0;
    o.y = *(const unsigned*)&h1;
    o.z = *(const unsigned*)&h2;
    o.w = *(const unsigned*)&h3;
    ((uint4*)dst)[i] = o;
}

// widen 8 packed halfs (one uint4) to fp32
__device__ __forceinline__ void cvt8(const uint4 r, float f[8]) {
    float2 q;
    q = __half22float2(*(const __half2*)&r.x); f[0] = q.x; f[1] = q.y;
    q = __half22float2(*(const __half2*)&r.y); f[2] = q.x; f[3] = q.y;
    q = __half22float2(*(const __half2*)&r.z); f[4] = q.x; f[5] = q.y;
    q = __half22float2(*(const __half2*)&r.w); f[6] = q.x; f[7] = q.y;
}

__device__ __forceinline__ void load8(const __half* __restrict__ p, float f[8]) {
    cvt8(*(const uint4*)p, f);
}

__device__ __forceinline__ void bfly8(float f[8], int m) {
#pragma unroll
    for (int j = 0; j < 8; ++j) f[j] += __shfl_xor(f[j], m, 64);
}

__global__ __launch_bounds__(256, 4) void KCDN_67997922230517_kernel(
    const int* __restrict__ items,
    const int* __restrict__ user_h, const int* __restrict__ user_t,
    const int* __restrict__ item_h, const int* __restrict__ item_t,
    const __half* __restrict__ tab, float* __restrict__ out) {
    __shared__ __align__(16) Smem sm;
    const int b    = blockIdx.x;
    const int tid  = threadIdx.x;
    const int w    = tid >> 6;     // 0,1=user L0,L1; 2,3=item L0,L1
    const int lane = tid & 63;
    const int oct  = lane >> 3;    // 8-lane octant owns one embedding per iter
    const int ol   = lane & 7;     // position in octant
    const int dstart = ol * 8;     // this lane's 8-dim slice

    // ---- stage this wave's 128 h + 128 t indices (wave-private, nt loads) ----
    {
        const int* hsrc; const int* tsrc; size_t off;
        if (w == 0)      { hsrc = user_h; tsrc = user_t; off = (size_t)b * NTRI; }
        else if (w == 1) { hsrc = user_h; tsrc = user_t; off = ((size_t)BATCH + b) * NTRI; }
        else if (w == 2) { hsrc = item_h; tsrc = item_t; off = (size_t)b * NTRI; }
        else             { hsrc = item_h; tsrc = item_t; off = ((size_t)BATCH + b) * NTRI; }
        *(v2i*)(&sm.idx[w][lane * 2]) =
            __builtin_nontemporal_load((const v2i*)(hsrc + off + lane * 2));
        *(v2i*)(&sm.idx[w][NTRI + lane * 2]) =
            __builtin_nontemporal_load((const v2i*)(tsrc + off + lane * 2));
        if (w == 1)
            *(v2i*)(&sm.meanidx[lane * 2]) =
                __builtin_nontemporal_load((const v2i*)(user_h + (size_t)b * NTRI + lane * 2));
    }

    // ---- user waves: prefetch first-half t-gathers NOW (loads depend only on
    //      indices; they complete under the mean/sim phases) ----
    uint4 tpre[8];
    if (w < 2) {
#pragma unroll
        for (int k = 0; k < 8; ++k) {
            const size_t id = (size_t)sm.idx[w][NTRI + oct * 16 + k];
            tpre[k] = *(const uint4*)(tab + id * DIM + dstart);
        }
    }

    // ---- anchor: 8 fp32 values per lane (replicated across octants) ----
    float anc[8];
    if (w >= 2) {
        const int it = __builtin_nontemporal_load(items + b);
        load8(tab + (size_t)it * DIM + dstart, anc);   // fp16 anchor (err ~5e-4)
    } else {
        // user_0 = mean over layer-0 h embeddings (waves 0,1 redundant; L1 merges)
        const int* mi = (w == 0) ? sm.idx[0] : sm.meanidx;
        float a[8] = {0, 0, 0, 0, 0, 0, 0, 0};
#pragma unroll 8
        for (int k = 0; k < 16; ++k) {
            const int e = oct * 16 + k;
            const size_t id = (size_t)mi[e];
            float f[8]; load8(tab + id * DIM + dstart, f);
#pragma unroll
            for (int j = 0; j < 8; ++j) a[j] += f[j];
        }
        bfly8(a, 8); bfly8(a, 16); bfly8(a, 32);
#pragma unroll
        for (int j = 0; j < 8; ++j) anc[j] = a[j] * (1.0f / 128.0f);
    }
    if (w == 0 && lane < 8) {
#pragma unroll
        for (int j = 0; j < 8; ++j) sm.anch_u[dstart + j] = anc[j];
    }
    if (w == 2 && lane < 8) {
#pragma unroll
        for (int j = 0; j < 8; ++j) sm.anch_v[dstart + j] = anc[j];
    }

    // ---- sims: each octant owns embeddings [oct*16, oct*16+16) ----
#pragma unroll 8
    for (int k = 0; k < 16; ++k) {
        const int e = oct * 16 + k;
        const size_t id = (size_t)sm.idx[w][e];
        float f[8]; load8(tab + id * DIM + dstart, f);
        float v = f[0] * anc[0] + f[1] * anc[1] + f[2] * anc[2] + f[3] * anc[3]
                + f[4] * anc[4] + f[5] * anc[5] + f[6] * anc[6] + f[7] * anc[7];
        v += __shfl_xor(v, 1, 64);
        v += __shfl_xor(v, 2, 64);
        v += __shfl_xor(v, 4, 64);
        if (ol == 0) sm.simw[w][k * 8 + oct] = v;   // permuted, conflict-free
    }

    // ---- softmax over this wave's 128 sims (order-invariant) ----
    {
        float v0 = sm.simw[w][lane];
        float v1 = sm.simw[w][lane + 64];
        float m = fmaxf(v0, v1);
#pragma unroll
        for (int off = 32; off; off >>= 1) m = fmaxf(m, __shfl_xor(m, off, 64));
        const float e0 = __expf(v0 - m), e1 = __expf(v1 - m);
        float s = e0 + e1;
#pragma unroll
        for (int off = 32; off; off >>= 1) s += __shfl_xor(s, off, 64);
        const float inv = 1.0f / s;
        sm.simw[w][lane]      = e0 * inv;
        sm.simw[w][lane + 64] = e1 * inv;
    }

    float acc[8] = {0, 0, 0, 0, 0, 0, 0, 0};
    if (w < 2) {
        // ---- user t-sum: no pruning (weights diffuse). Issue second-half
        //      loads first, then consume prefetched first half. ----
        uint4 t2[8];
#pragma unroll
        for (int k = 0; k < 8; ++k) {
            const size_t id = (size_t)sm.idx[w][NTRI + oct * 16 + 8 + k];
            t2[k] = *(const uint4*)(tab + id * DIM + dstart);
        }
#pragma unroll
        for (int k = 0; k < 8; ++k) {
            const float wt = sm.simw[w][k * 8 + oct];
            float f[8]; cvt8(tpre[k], f);
#pragma unroll
            for (int j = 0; j < 8; ++j) acc[j] += wt * f[j];
        }
#pragma unroll
        for (int k = 0; k < 8; ++k) {
            const float wt = sm.simw[w][(8 + k) * 8 + oct];
            float f[8]; cvt8(t2[k], f);
#pragma unroll
            for (int j = 0; j < 8; ++j) acc[j] += wt * f[j];
        }
    } else {
        // ---- item t-sum: compact (idx, weight) with weight > WTH ----
        const int cs = w - 2;
        int nkeep;
        {
            const float w0 = sm.simw[w][lane];
            const float w1 = sm.simw[w][lane + 64];
            const int s0 = ((lane & 7) << 4) | (lane >> 3);
            const int s1 = ((lane & 7) << 4) | ((lane >> 3) + 8);
            const bool k0 = w0 > WTH, k1 = w1 > WTH;
            const unsigned long long b0 = __ballot(k0);
            const unsigned long long b1 = __ballot(k1);
            const int c0 = __popcll(b0);
            const unsigned long long below = (1ull << lane) - 1ull;
            const int p0 = __popcll(b0 & below);
            const int p1 = c0 + __popcll(b1 & below);
            if (k0) { sm.cidx[cs][p0] = sm.idx[w][NTRI + s0]; sm.cw[cs][p0] = w0; }
            if (k1) { sm.cidx[cs][p1] = sm.idx[w][NTRI + s1]; sm.cw[cs][p1] = w1; }
            nkeep = c0 + __popcll(b1);   // wave-uniform
        }
        for (int e = oct; e < nkeep; e += 8) {
            const size_t id = (size_t)sm.cidx[cs][e];   // broadcast within octant
            const float wt = sm.cw[cs][e];
            float f[8]; load8(tab + id * DIM + dstart, f);
#pragma unroll
            for (int j = 0; j < 8; ++j) acc[j] += wt * f[j];
        }
    }
    bfly8(acc, 8); bfly8(acc, 16); bfly8(acc, 32);
    if (lane < 8) {
#pragma unroll
        for (int j = 0; j < 8; ++j) sm.res[w][dstart + j] = acc[j];
    }

    __syncthreads();   // the only block-wide barrier

    // ---- final: sigmoid(e_v . e_u) ----
    if (tid < 64) {
        const float eu = sm.anch_u[tid] + sm.res[0][tid] + sm.res[1][tid];
        const float ev = sm.anch_v[tid] + sm.res[2][tid] + sm.res[3][tid];
        float v = eu * ev;
#pragma unroll
        for (int off = 32; off; off >>= 1) v += __shfl_xor(v, off, 64);
        if (tid == 0) out[b] = 1.0f / (1.0f + __expf(-v));
    }
}

extern "C" void kernel_launch(void* const* d_in, const int* in_sizes, int n_in,
                              void* d_out, int out_size, void* d_ws, size_t ws_size,
                              hipStream_t stream) {
    // d_in: items, user_h, user_r, user_t, item_h, item_r, item_t,
    //       entity_emb, relation_emb (r / relation_emb unused by reference)
    const int*   items  = (const int*)d_in[0];
    const int*   user_h = (const int*)d_in[1];
    const int*   user_t = (const int*)d_in[3];
    const int*   item_h = (const int*)d_in[4];
    const int*   item_t = (const int*)d_in[6];
    const float* ent    = (const float*)d_in[7];
    float*       out    = (float*)d_out;
    __half*      tab    = (__half*)d_ws;          // 100000*64*2 B = 12.8 MB

    const int n8 = NENT * DIM / 8;                // 800000 threads, 8 floats each
    hipLaunchKernelGGL(convert_fp16, dim3((n8 + 255) / 256), dim3(256), 0, stream,
                       ent, tab, n8);
    hipLaunchKernelGGL(KCDN_67997922230517_kernel, dim3(BATCH), dim3(256), 0, stream,
                       items, user_h, user_t, item_h, item_t, tab, out);
}

// Round 6
// 148.803 us; speedup vs baseline: 1.0632x; 1.0632x over previous
//
#include <hip/hip_runtime.h>
#include <hip/hip_fp16.h>

#define BATCH 4096
#define NTRI  128
#define DIM   64
#define NENT  100000
#define WTH   1e-5f   // drop tail-gathers with softmax weight below this

typedef int   v2i __attribute__((ext_vector_type(2)));
typedef float v4f __attribute__((ext_vector_type(4)));

// LDS: per-wave-private except res/anchors (guarded by the single __syncthreads).
struct Smem {
    int   idx[4][2 * NTRI];   // per-set: h in [0..127], t in [128..255]
    int   meanidx[NTRI];      // wave-1 private copy of user layer-0 h indices
    float simw[4][NTRI];      // sims -> weights, permuted: pos = k*8+oct
    int   cidx[4][NTRI];      // compacted t-indices (weight > WTH)
    float cw[4][NTRI];        // compacted weights
    float res[4][DIM];        // per-wave attention results
    float anch_u[DIM];        // user_0 mean   (written by wave 0)
    float anch_v[DIM];        // item origin   (written by wave 2)
};

// ---- fp32 -> fp16 table conversion (every launch; d_ws is re-poisoned) ----
__global__ __launch_bounds__(256) void convert_fp16(
    const float* __restrict__ src, __half* __restrict__ dst, int n8) {
    const int i = blockIdx.x * 256 + threadIdx.x;   // 8 floats per thread
    if (i >= n8) return;
    const v4f a = __builtin_nontemporal_load((const v4f*)src + 2 * i);
    const v4f b = __builtin_nontemporal_load((const v4f*)src + 2 * i + 1);
    __half2 h0 = __floats2half2_rn(a.x, a.y);
    __half2 h1 = __floats2half2_rn(a.z, a.w);
    __half2 h2 = __floats2half2_rn(b.x, b.y);
    __half2 h3 = __floats2half2_rn(b.z, b.w);
    uint4 o;
    o.x = *(const unsigned*)&h0;
    o.y = *(const unsigned*)&h1;
    o.z = *(const unsigned*)&h2;
    o.w = *(const unsigned*)&h3;
    ((uint4*)dst)[i] = o;
}

// widen 8 packed halfs (one uint4) to fp32
__device__ __forceinline__ void cvt8(const uint4 r, float f[8]) {
    float2 q;
    q = __half22float2(*(const __half2*)&r.x); f[0] = q.x; f[1] = q.y;
    q = __half22float2(*(const __half2*)&r.y); f[2] = q.x; f[3] = q.y;
    q = __half22float2(*(const __half2*)&r.z); f[4] = q.x; f[5] = q.y;
    q = __half22float2(*(const __half2*)&r.w); f[6] = q.x; f[7] = q.y;
}

__device__ __forceinline__ void load8(const __half* __restrict__ p, float f[8]) {
    cvt8(*(const uint4*)p, f);
}

__device__ __forceinline__ void bfly8(float f[8], int m) {
#pragma unroll
    for (int j = 0; j < 8; ++j) f[j] += __shfl_xor(f[j], m, 64);
}

__global__ __launch_bounds__(256) void KCDN_67997922230517_kernel(
    const int* __restrict__ items,
    const int* __restrict__ user_h, const int* __restrict__ user_t,
    const int* __restrict__ item_h, const int* __restrict__ item_t,
    const float* __restrict__ ent, const __half* __restrict__ tab,
    float* __restrict__ out) {
    __shared__ __align__(16) Smem sm;
    const int b    = blockIdx.x;
    const int tid  = threadIdx.x;
    const int w    = tid >> 6;     // 0,1=user L0,L1; 2,3=item L0,L1
    const int lane = tid & 63;
    const int oct  = lane >> 3;    // 8-lane octant owns one embedding per iter
    const int ol   = lane & 7;     // position in octant
    const int dstart = ol * 8;     // this lane's 8-dim slice

    // ---- stage this wave's 128 h + 128 t indices (wave-private, nt loads) ----
    {
        const int* hsrc; const int* tsrc; size_t off;
        if (w == 0)      { hsrc = user_h; tsrc = user_t; off = (size_t)b * NTRI; }
        else if (w == 1) { hsrc = user_h; tsrc = user_t; off = ((size_t)BATCH + b) * NTRI; }
        else if (w == 2) { hsrc = item_h; tsrc = item_t; off = (size_t)b * NTRI; }
        else             { hsrc = item_h; tsrc = item_t; off = ((size_t)BATCH + b) * NTRI; }
        *(v2i*)(&sm.idx[w][lane * 2]) =
            __builtin_nontemporal_load((const v2i*)(hsrc + off + lane * 2));
        *(v2i*)(&sm.idx[w][NTRI + lane * 2]) =
            __builtin_nontemporal_load((const v2i*)(tsrc + off + lane * 2));
        if (w == 1)
            *(v2i*)(&sm.meanidx[lane * 2]) =
                __builtin_nontemporal_load((const v2i*)(user_h + (size_t)b * NTRI + lane * 2));
    }

    // ---- anchor: 8 fp32 values per lane (replicated across octants) ----
    float anc[8];
    if (w >= 2) {
        const int it = __builtin_nontemporal_load(items + b);
        const size_t ii = (size_t)it * DIM + dstart;
        const v4f a0 = __builtin_nontemporal_load((const v4f*)(ent + ii));
        const v4f a1 = __builtin_nontemporal_load((const v4f*)(ent + ii + 4));
        anc[0] = a0.x; anc[1] = a0.y; anc[2] = a0.z; anc[3] = a0.w;
        anc[4] = a1.x; anc[5] = a1.y; anc[6] = a1.z; anc[7] = a1.w;
    } else {
        // user_0 = mean over layer-0 h embeddings (wave 1's repeats hit L1)
        const int* mi = (w == 0) ? sm.idx[0] : sm.meanidx;
        float a[8] = {0, 0, 0, 0, 0, 0, 0, 0};
#pragma unroll 4
        for (int k = 0; k < 16; ++k) {
            const int e = oct * 16 + k;
            const size_t id = (size_t)mi[e];
            float f[8]; load8(tab + id * DIM + dstart, f);
#pragma unroll
            for (int j = 0; j < 8; ++j) a[j] += f[j];
        }
        bfly8(a, 8); bfly8(a, 16); bfly8(a, 32);
#pragma unroll
        for (int j = 0; j < 8; ++j) anc[j] = a[j] * (1.0f / 128.0f);
    }
    if (w == 0 && lane < 8) {
#pragma unroll
        for (int j = 0; j < 8; ++j) sm.anch_u[dstart + j] = anc[j];
    }
    if (w == 2 && lane < 8) {
#pragma unroll
        for (int j = 0; j < 8; ++j) sm.anch_v[dstart + j] = anc[j];
    }

    // ---- sims: each octant owns embeddings [oct*16, oct*16+16) ----
#pragma unroll 4
    for (int k = 0; k < 16; ++k) {
        const int e = oct * 16 + k;
        const size_t id = (size_t)sm.idx[w][e];
        float f[8]; load8(tab + id * DIM + dstart, f);
        float v = f[0] * anc[0] + f[1] * anc[1] + f[2] * anc[2] + f[3] * anc[3]
                + f[4] * anc[4] + f[5] * anc[5] + f[6] * anc[6] + f[7] * anc[7];
        v += __shfl_xor(v, 1, 64);
        v += __shfl_xor(v, 2, 64);
        v += __shfl_xor(v, 4, 64);
        if (ol == 0) sm.simw[w][k * 8 + oct] = v;   // permuted, conflict-free
    }

    // ---- softmax over this wave's 128 sims (order-invariant) ----
    {
        float v0 = sm.simw[w][lane];
        float v1 = sm.simw[w][lane + 64];
        float m = fmaxf(v0, v1);
#pragma unroll
        for (int off = 32; off; off >>= 1) m = fmaxf(m, __shfl_xor(m, off, 64));
        const float e0 = __expf(v0 - m), e1 = __expf(v1 - m);
        float s = e0 + e1;
#pragma unroll
        for (int off = 32; off; off >>= 1) s += __shfl_xor(s, off, 64);
        const float inv = 1.0f / s;
        sm.simw[w][lane]      = e0 * inv;
        sm.simw[w][lane + 64] = e1 * inv;
    }

    // ---- compact (t-index, weight) pairs with weight > WTH ----
    // permuted pos p -> triple slot s(p) = ((p&7)<<4) | (p>>3)
    int nkeep;
    {
        const float w0 = sm.simw[w][lane];
        const float w1 = sm.simw[w][lane + 64];
        const int s0 = ((lane & 7) << 4) | (lane >> 3);
        const int s1 = ((lane & 7) << 4) | ((lane >> 3) + 8);
        const bool k0 = w0 > WTH, k1 = w1 > WTH;
        const unsigned long long b0 = __ballot(k0);
        const unsigned long long b1 = __ballot(k1);
        const int c0 = __popcll(b0);
        const unsigned long long below = (1ull << lane) - 1ull;
        const int p0 = __popcll(b0 & below);
        const int p1 = c0 + __popcll(b1 & below);
        if (k0) { sm.cidx[w][p0] = sm.idx[w][NTRI + s0]; sm.cw[w][p0] = w0; }
        if (k1) { sm.cidx[w][p1] = sm.idx[w][NTRI + s1]; sm.cw[w][p1] = w1; }
        nkeep = c0 + __popcll(b1);   // wave-uniform
    }

    // ---- weighted sum over surviving tail embeddings, 2-wide pipelined ----
    float acc[8] = {0, 0, 0, 0, 0, 0, 0, 0};
    {
        int e = oct;
        for (; e + 8 < nkeep; e += 16) {
            const int   id0 = sm.cidx[w][e];
            const int   id1 = sm.cidx[w][e + 8];
            const float wt0 = sm.cw[w][e];
            const float wt1 = sm.cw[w][e + 8];
            const uint4 r0 = *(const uint4*)(tab + (size_t)id0 * DIM + dstart);
            const uint4 r1 = *(const uint4*)(tab + (size_t)id1 * DIM + dstart);
            float f[8];
            cvt8(r0, f);
#pragma unroll
            for (int j = 0; j < 8; ++j) acc[j] += wt0 * f[j];
            cvt8(r1, f);
#pragma unroll
            for (int j = 0; j < 8; ++j) acc[j] += wt1 * f[j];
        }
        if (e < nkeep) {
            const int   id0 = sm.cidx[w][e];
            const float wt0 = sm.cw[w][e];
            float f[8]; load8(tab + (size_t)id0 * DIM + dstart, f);
#pragma unroll
            for (int j = 0; j < 8; ++j) acc[j] += wt0 * f[j];
        }
    }
    bfly8(acc, 8); bfly8(acc, 16); bfly8(acc, 32);
    if (lane < 8) {
#pragma unroll
        for (int j = 0; j < 8; ++j) sm.res[w][dstart + j] = acc[j];
    }

    __syncthreads();   // the only block-wide barrier

    // ---- final: sigmoid(e_v . e_u) ----
    if (tid < 64) {
        const float eu = sm.anch_u[tid] + sm.res[0][tid] + sm.res[1][tid];
        const float ev = sm.anch_v[tid] + sm.res[2][tid] + sm.res[3][tid];
        float v = eu * ev;
#pragma unroll
        for (int off = 32; off; off >>= 1) v += __shfl_xor(v, off, 64);
        if (tid == 0) out[b] = 1.0f / (1.0f + __expf(-v));
    }
}

extern "C" void kernel_launch(void* const* d_in, const int* in_sizes, int n_in,
                              void* d_out, int out_size, void* d_ws, size_t ws_size,
                              hipStream_t stream) {
    // d_in: items, user_h, user_r, user_t, item_h, item_r, item_t,
    //       entity_emb, relation_emb (r / relation_emb unused by reference)
    const int*   items  = (const int*)d_in[0];
    const int*   user_h = (const int*)d_in[1];
    const int*   user_t = (const int*)d_in[3];
    const int*   item_h = (const int*)d_in[4];
    const int*   item_t = (const int*)d_in[6];
    const float* ent    = (const float*)d_in[7];
    float*       out    = (float*)d_out;
    __half*      tab    = (__half*)d_ws;          // 100000*64*2 B = 12.8 MB

    const int n8 = NENT * DIM / 8;                // 800000 threads, 8 floats each
    hipLaunchKernelGGL(convert_fp16, dim3((n8 + 255) / 256), dim3(256), 0, stream,
                       ent, tab, n8);
    hipLaunchKernelGGL(KCDN_67997922230517_kernel, dim3(BATCH), dim3(256), 0, stream,
                       items, user_h, user_t, item_h, item_t, ent, tab, out);
}